// Round 15
// baseline (100.118 us; speedup 1.0000x reference)
//
#include <hip/hip_runtime.h>

// Bicubic (Catmull-Rom) warped interpolation.
// LDS-tiled, f16 DUAL-PHASE layout + v_dot2_f32_f16 tap combine.
// img/delta_x/delta_y: [B,C,H,W] fp32; out: fp32 clipped to [0,1]. H=W=1024.
// 64x64 tile / 256 threads. Patch (76 rows x 81 cols) staged in LDS as f16
// pairs in TWO phase-shifted copies (copy0 dword j = elems (2j,2j+1); copy1 =
// (2j+1,2j+2)); 4-tap row window lx..lx+3 = 2 ADJACENT dwords of copy (lx&1)
// -> per pixel 4 ds_read2_b32 / 8 dword-accesses (vs 8/16 in fp32 round 13).
// Dword row-stride 64 == 0 mod 32 -> bank = (lane + x-jitter)/2: jitter
// halved, lane-pairs broadcast -> conflicts well below half. No unpack VALU:
// rows combine via v_dot2_f32_f16 (f32 accumulate); weights packed to half2
// by cvt_pkrtz; staging converts by cvt_pkrtz (1 op per 2 floats).
// Delta loads hoisted (R6 win). Rare fp32 global fallback (|delta| > ~5).

#define HD 1024
#define WD 1024
#define TILE 64
#define HALOX 8     // x halo (keeps gx0 16B-aligned for float4 staging)
#define HALOY 6     // y halo (76 rows keeps LDS at 4 blocks/CU)
#define SROWS 76    // staged rows
#define DSTR 64     // dword stride per row (64 % 32 == 0 -> bank win)
#define COFF 4864   // copy1 offset in dwords (76*64)

typedef __attribute__((ext_vector_type(2))) _Float16 f16x2;   // fdot2 operand type
typedef __attribute__((ext_vector_type(2))) __fp16   h16x2;   // cvt_pkrtz return type
typedef __attribute__((ext_vector_type(2))) float    f32x2;

__device__ __forceinline__ float cubic_gather_global(
    const float* __restrict__ p, int x0, int y0,
    float wxm1, float wx0, float wx1, float wx2,
    float wym1, float wy0, float wy1, float wy2)
{
    int cx0 = min(max(x0 - 1, 0), WD - 1);
    int cx1 = min(max(x0,     0), WD - 1);
    int cx2 = min(max(x0 + 1, 0), WD - 1);
    int cx3 = min(max(x0 + 2, 0), WD - 1);
    int cy0 = min(max(y0 - 1, 0), HD - 1);
    int cy1 = min(max(y0,     0), HD - 1);
    int cy2 = min(max(y0 + 1, 0), HD - 1);
    int cy3 = min(max(y0 + 2, 0), HD - 1);
    const float* r0 = p + (size_t)cy0 * WD;
    const float* r1 = p + (size_t)cy1 * WD;
    const float* r2 = p + (size_t)cy2 * WD;
    const float* r3 = p + (size_t)cy3 * WD;
    float s0 = wxm1 * r0[cx0] + wx0 * r0[cx1] + wx1 * r0[cx2] + wx2 * r0[cx3];
    float s1 = wxm1 * r1[cx0] + wx0 * r1[cx1] + wx1 * r1[cx2] + wx2 * r1[cx3];
    float s2 = wxm1 * r2[cx0] + wx0 * r2[cx1] + wx1 * r2[cx2] + wx2 * r2[cx3];
    float s3 = wxm1 * r3[cx0] + wx0 * r3[cx1] + wx1 * r3[cx2] + wx2 * r3[cx3];
    return wym1 * s0 + wy0 * s1 + wy1 * s2 + wy2 * s3;
}

__device__ __forceinline__ uint32_t pk16(float a, float b) {
    h16x2 h = __builtin_amdgcn_cvt_pkrtz(a, b);
    return __builtin_bit_cast(uint32_t, h);
}
__device__ __forceinline__ f16x2 u2h(uint32_t u) {
    return __builtin_bit_cast(f16x2, u);
}

__global__ __launch_bounds__(256) void bicubic_tile_kernel(
    const float* __restrict__ img,
    const float* __restrict__ dxp,
    const float* __restrict__ dyp,
    float* __restrict__ out)
{
    __shared__ uint32_t smp[2 * COFF];   // 38.9 KB -> 4 blocks/CU

    const int bx = blockIdx.x * TILE;
    const int by = blockIdx.y * TILE;
    const int plane = blockIdx.z;
    const float* __restrict__ p = img + (size_t)plane * (size_t)(HD * WD);

    const int gx0 = bx - HALOX;
    const int gy0 = by - HALOY;
    const int tid = threadIdx.x;

    // ---- stage 76 rows x 81 cols as dual-phase f16 pairs (edge-clamped) ----
    if (gx0 >= 0 && gx0 + 80 <= WD - 1) {
        // interior: 20 float4 quads + 1 scalar per row
        for (int s = tid; s < SROWS * 20; s += 256) {
            int r = s / 20;
            int q = s - r * 20;
            int gy = min(max(gy0 + r, 0), HD - 1);
            const float* rowp = p + (size_t)gy * WD + gx0;
            float4 v = *reinterpret_cast<const float4*>(rowp + 4 * q);
            float v4 = rowp[4 * q + 4];
            int b = r * DSTR + 2 * q;
            smp[b]            = pk16(v.x, v.y);   // c0: (4q,   4q+1)
            smp[b + 1]        = pk16(v.z, v.w);   // c0: (4q+2, 4q+3)
            smp[COFF + b]     = pk16(v.y, v.z);   // c1: (4q+1, 4q+2)
            smp[COFF + b + 1] = pk16(v.w, v4);    // c1: (4q+3, 4q+4)
        }
    } else {
        // edge tile: per-pair scalar staging with clamp
        for (int s = tid; s < SROWS * 40; s += 256) {
            int r = s / 40;
            int j = s - r * 40;
            int gy = min(max(gy0 + r, 0), HD - 1);
            const float* rowp = p + (size_t)gy * WD;
            int e0 = min(max(gx0 + 2 * j,     0), WD - 1);
            int e1 = min(max(gx0 + 2 * j + 1, 0), WD - 1);
            int e2 = min(max(gx0 + 2 * j + 2, 0), WD - 1);
            float v0 = rowp[e0], v1 = rowp[e1], v2 = rowp[e2];
            int b = r * DSTR + j;
            smp[b]        = pk16(v0, v1);
            smp[COFF + b] = pk16(v1, v2);
        }
    }
    __syncthreads();

    // ---- compute: lane = column (64 consecutive cols/wave), 16 rows/thread
    const int col = bx + (tid & 63);
    const int rbase = by + (tid >> 6);
    const int didx0 = (plane << 20) | (rbase << 10) | col;

    // hoisted delta loads (R6 win: HBM latency hides under compute)
    float vdx[16], vdy[16];
    #pragma unroll
    for (int it = 0; it < 16; ++it) {
        vdx[it] = dxp[didx0 + it * 4096];
        vdy[it] = dyp[didx0 + it * 4096];
    }

    // x_map = ((x + dx - 512)/511 + 1)*511.5 == (x-512)*sc + 511.5 + dx*sc
    const float sc = 511.5f / 511.0f;
    const float colA = ((float)col - 512.0f) * sc + 511.5f;
    const float yA0 = ((float)rbase - 512.0f) * sc + 511.5f;
    const float yStep = 4.0f * sc;

    // packed polynomial constants
    const f32x2 cN05 = {-0.5f, -0.5f};
    const f32x2 cP05 = { 0.5f,  0.5f};
    const f32x2 cP1  = { 1.0f,  1.0f};
    const f32x2 cN1  = {-1.0f, -1.0f};
    const f32x2 cP2  = { 2.0f,  2.0f};
    const f32x2 cN25 = {-2.5f, -2.5f};
    const f32x2 cP15 = { 1.5f,  1.5f};
    const f32x2 cN15 = {-1.5f, -1.5f};

    #pragma unroll
    for (int it = 0; it < 16; ++it) {
        const int didx = didx0 + it * 4096;
        const float ddx = vdx[it];
        const float ddy = vdy[it];

        float x_map = fmaf(ddx, sc, colA);
        float y_map = fmaf(ddy, sc, yA0 + (float)it * yStep);

        float x0f = floorf(x_map);
        float y0f = floorf(y_map);
        int x0 = (int)x0f;
        int y0 = (int)y0f;

        // packed weights: .x = x-direction, .y = y-direction
        f32x2 t;
        t.x = x_map - x0f;
        t.y = y_map - y0f;
        f32x2 t2v = t * t;
        f32x2 t3v = t2v * t;
        f32x2 wm1 = __builtin_elementwise_fma(t3v, cN05,
                        __builtin_elementwise_fma(t, cN05, t2v));
        f32x2 w0v = __builtin_elementwise_fma(t3v, cP15,
                        __builtin_elementwise_fma(t2v, cN25, cP1));
        f32x2 w1v = __builtin_elementwise_fma(t3v, cN15,
                        __builtin_elementwise_fma(t2v, cP2, t * cP05));
        f32x2 w2v = __builtin_elementwise_fma(wm1 + w0v + w1v, cN1, cP1);

        const int lx = x0 - 1 - gx0;
        const int ly = y0 - 1 - gy0;
        const bool inb = ((unsigned)lx <= 76u) & ((unsigned)ly <= 72u);

        float acc;
        if (inb) {
            // x-weights to half2 (RTZ; |err| <= 2^-11 of weight)
            f16x2 wxa = u2h(pk16(wm1.x, w0v.x));
            f16x2 wxb = u2h(pk16(w1v.x, w2v.x));
            const int base = ((lx & 1) ? COFF : 0) + ly * DSTR + (lx >> 1);
            // 4 rows x one ds_read2_b32 (adjacent dwords) each
            uint32_t a0 = smp[base],            a1 = smp[base + 1];
            uint32_t b0 = smp[base + DSTR],     b1 = smp[base + DSTR + 1];
            uint32_t c0 = smp[base + 2 * DSTR], c1 = smp[base + 2 * DSTR + 1];
            uint32_t d0 = smp[base + 3 * DSTR], d1 = smp[base + 3 * DSTR + 1];
            float s0 = __builtin_amdgcn_fdot2(wxa, u2h(a0),
                         __builtin_amdgcn_fdot2(wxb, u2h(a1), 0.0f, false), false);
            float s1 = __builtin_amdgcn_fdot2(wxa, u2h(b0),
                         __builtin_amdgcn_fdot2(wxb, u2h(b1), 0.0f, false), false);
            float s2 = __builtin_amdgcn_fdot2(wxa, u2h(c0),
                         __builtin_amdgcn_fdot2(wxb, u2h(c1), 0.0f, false), false);
            float s3 = __builtin_amdgcn_fdot2(wxa, u2h(d0),
                         __builtin_amdgcn_fdot2(wxb, u2h(d1), 0.0f, false), false);
            acc = wm1.y * s0 + w0v.y * s1 + w1v.y * s2 + w2v.y * s3;
        } else {
            acc = cubic_gather_global(p, x0, y0, wm1.x, w0v.x, w1v.x, w2v.x,
                                      wm1.y, w0v.y, w1v.y, w2v.y);
        }
        out[didx] = fminf(fmaxf(acc, 0.0f), 1.0f);
    }
}

extern "C" void kernel_launch(void* const* d_in, const int* in_sizes, int n_in,
                              void* d_out, int out_size, void* d_ws, size_t ws_size,
                              hipStream_t stream) {
    const float* img = (const float*)d_in[0];
    const float* dxp = (const float*)d_in[1];
    const float* dyp = (const float*)d_in[2];
    float* out = (float*)d_out;

    const int planes = in_sizes[0] / (HD * WD);  // B*C = 24
    dim3 grid(WD / TILE, HD / TILE, planes);
    bicubic_tile_kernel<<<grid, 256, 0, stream>>>(img, dxp, dyp, out);
}

// Round 16
// 94.326 us; speedup vs baseline: 1.0614x; 1.0614x over previous
//
#include <hip/hip_runtime.h>

// Bicubic (Catmull-Rom) warped interpolation.
// LDS-tiled, f16 SINGLE-copy layout + alignbit phase-select + fdot2 combine.
// img/delta_x/delta_y: [B,C,H,W] fp32; out: fp32 clipped to [0,1]. H=W=1024.
// 64x64 tile / 256 threads. Patch (76 rows x 84 cols) staged in LDS as f16
// pairs, ONE copy, row stride 64 dwords (42 used; stride % 32 == 0 -> bank =
// (lane + x-jitter)/2, y-jitter free). Per tap row read 3 consecutive dwords
// (6 f16) from one vaddr via ds_read2_b32 x1.5 -> per pixel 6 LDS instrs /
// 12 dword-accesses (vs 16 in fp32 R13), then select the 4-tap window by
// parity with v_alignbit_b32 (shift = (lx&1)*16) feeding v_dot2_f32_f16.
// 19.5 KB LDS -> 8 blocks/CU (2048-thread cap, 100% occupancy potential).
// Weights packed fp32 (R13 win); delta loads hoisted (R6 win).
// Rare fp32 global fallback (|delta| > ~6).

#define HD 1024
#define WD 1024
#define TILE 64
#define HALOX 8     // x halo left (stage 84 floats: 8 + 64 + 12)
#define HALOY 6     // y halo (76 rows)
#define SROWS 76    // staged rows
#define SCOLS 84    // staged floats per row
#define DSTR 64     // dword stride per row (64 % 32 == 0 -> bank win)

typedef __attribute__((ext_vector_type(2))) _Float16 f16x2;   // fdot2 operand type
typedef __attribute__((ext_vector_type(2))) __fp16   h16x2;   // cvt_pkrtz return type
typedef __attribute__((ext_vector_type(2))) float    f32x2;

__device__ __forceinline__ float cubic_gather_global(
    const float* __restrict__ p, int x0, int y0,
    float wxm1, float wx0, float wx1, float wx2,
    float wym1, float wy0, float wy1, float wy2)
{
    int cx0 = min(max(x0 - 1, 0), WD - 1);
    int cx1 = min(max(x0,     0), WD - 1);
    int cx2 = min(max(x0 + 1, 0), WD - 1);
    int cx3 = min(max(x0 + 2, 0), WD - 1);
    int cy0 = min(max(y0 - 1, 0), HD - 1);
    int cy1 = min(max(y0,     0), HD - 1);
    int cy2 = min(max(y0 + 1, 0), HD - 1);
    int cy3 = min(max(y0 + 2, 0), HD - 1);
    const float* r0 = p + (size_t)cy0 * WD;
    const float* r1 = p + (size_t)cy1 * WD;
    const float* r2 = p + (size_t)cy2 * WD;
    const float* r3 = p + (size_t)cy3 * WD;
    float s0 = wxm1 * r0[cx0] + wx0 * r0[cx1] + wx1 * r0[cx2] + wx2 * r0[cx3];
    float s1 = wxm1 * r1[cx0] + wx0 * r1[cx1] + wx1 * r1[cx2] + wx2 * r1[cx3];
    float s2 = wxm1 * r2[cx0] + wx0 * r2[cx1] + wx1 * r2[cx2] + wx2 * r2[cx3];
    float s3 = wxm1 * r3[cx0] + wx0 * r3[cx1] + wx1 * r3[cx2] + wx2 * r3[cx3];
    return wym1 * s0 + wy0 * s1 + wy1 * s2 + wy2 * s3;
}

__device__ __forceinline__ uint32_t pk16(float a, float b) {
    h16x2 h = __builtin_amdgcn_cvt_pkrtz(a, b);
    return __builtin_bit_cast(uint32_t, h);
}
__device__ __forceinline__ f16x2 u2h(uint32_t u) {
    return __builtin_bit_cast(f16x2, u);
}

__global__ __launch_bounds__(256) void bicubic_tile_kernel(
    const float* __restrict__ img,
    const float* __restrict__ dxp,
    const float* __restrict__ dyp,
    float* __restrict__ out)
{
    __shared__ uint32_t smp[SROWS * DSTR];   // 19.5 KB -> 8 blocks/CU

    const int bx = blockIdx.x * TILE;
    const int by = blockIdx.y * TILE;
    const int plane = blockIdx.z;
    const float* __restrict__ p = img + (size_t)plane * (size_t)(HD * WD);

    const int gx0 = bx - HALOX;
    const int gy0 = by - HALOY;
    const int tid = threadIdx.x;

    // ---- stage 76 rows x 84 floats as f16 pairs (42 dwords/row) ----
    if (gx0 >= 0 && gx0 + SCOLS <= WD) {
        // interior: 21 float4 quads per row -> 2 packed dwords each
        for (int s = tid; s < SROWS * 21; s += 256) {
            int r = s / 21;
            int q = s - r * 21;
            int gy = min(max(gy0 + r, 0), HD - 1);
            const float* rowp = p + (size_t)gy * WD + gx0;
            float4 v = *reinterpret_cast<const float4*>(rowp + 4 * q);
            int b = r * DSTR + 2 * q;
            smp[b]     = pk16(v.x, v.y);
            smp[b + 1] = pk16(v.z, v.w);
        }
    } else {
        // edge tile: per-dword scalar staging with clamp
        for (int s = tid; s < SROWS * 42; s += 256) {
            int r = s / 42;
            int j = s - r * 42;
            int gy = min(max(gy0 + r, 0), HD - 1);
            const float* rowp = p + (size_t)gy * WD;
            int e0 = min(max(gx0 + 2 * j,     0), WD - 1);
            int e1 = min(max(gx0 + 2 * j + 1, 0), WD - 1);
            smp[r * DSTR + j] = pk16(rowp[e0], rowp[e1]);
        }
    }
    __syncthreads();

    // ---- compute: lane = column (64 consecutive cols/wave), 16 rows/thread
    const int col = bx + (tid & 63);
    const int rbase = by + (tid >> 6);
    const int didx0 = (plane << 20) | (rbase << 10) | col;

    // hoisted delta loads (R6 win: HBM latency hides under compute)
    float vdx[16], vdy[16];
    #pragma unroll
    for (int it = 0; it < 16; ++it) {
        vdx[it] = dxp[didx0 + it * 4096];
        vdy[it] = dyp[didx0 + it * 4096];
    }

    // x_map = ((x + dx - 512)/511 + 1)*511.5 == (x-512)*sc + 511.5 + dx*sc
    const float sc = 511.5f / 511.0f;
    const float colA = ((float)col - 512.0f) * sc + 511.5f;
    const float yA0 = ((float)rbase - 512.0f) * sc + 511.5f;
    const float yStep = 4.0f * sc;

    // packed polynomial constants
    const f32x2 cN05 = {-0.5f, -0.5f};
    const f32x2 cP05 = { 0.5f,  0.5f};
    const f32x2 cP1  = { 1.0f,  1.0f};
    const f32x2 cN1  = {-1.0f, -1.0f};
    const f32x2 cP2  = { 2.0f,  2.0f};
    const f32x2 cN25 = {-2.5f, -2.5f};
    const f32x2 cP15 = { 1.5f,  1.5f};
    const f32x2 cN15 = {-1.5f, -1.5f};

    #pragma unroll
    for (int it = 0; it < 16; ++it) {
        const int didx = didx0 + it * 4096;
        const float ddx = vdx[it];
        const float ddy = vdy[it];

        float x_map = fmaf(ddx, sc, colA);
        float y_map = fmaf(ddy, sc, yA0 + (float)it * yStep);

        float x0f = floorf(x_map);
        float y0f = floorf(y_map);
        int x0 = (int)x0f;
        int y0 = (int)y0f;

        // packed weights: .x = x-direction, .y = y-direction
        f32x2 t;
        t.x = x_map - x0f;
        t.y = y_map - y0f;
        f32x2 t2v = t * t;
        f32x2 t3v = t2v * t;
        f32x2 wm1 = __builtin_elementwise_fma(t3v, cN05,
                        __builtin_elementwise_fma(t, cN05, t2v));
        f32x2 w0v = __builtin_elementwise_fma(t3v, cP15,
                        __builtin_elementwise_fma(t2v, cN25, cP1));
        f32x2 w1v = __builtin_elementwise_fma(t3v, cN15,
                        __builtin_elementwise_fma(t2v, cP2, t * cP05));
        f32x2 w2v = __builtin_elementwise_fma(wm1 + w0v + w1v, cN1, cP1);

        const int lx = x0 - 1 - gx0;
        const int ly = y0 - 1 - gy0;
        const bool inb = ((unsigned)lx <= 76u) & ((unsigned)ly <= (unsigned)(SROWS - 4));

        float acc;
        if (inb) {
            // x-weights to half2 (RTZ; |err| <= 2^-11 of weight)
            f16x2 wxa = u2h(pk16(wm1.x, w0v.x));
            f16x2 wxb = u2h(pk16(w1v.x, w2v.x));
            const int base = ly * DSTR + (lx >> 1);
            const uint32_t sh = (uint32_t)((lx & 1) << 4);
            // 4 rows x 3 consecutive dwords (6 f16 covers both parities)
            uint32_t a0 = smp[base],            a1 = smp[base + 1],            a2 = smp[base + 2];
            uint32_t b0 = smp[base + DSTR],     b1 = smp[base + DSTR + 1],     b2 = smp[base + DSTR + 2];
            uint32_t c0 = smp[base + 2 * DSTR], c1 = smp[base + 2 * DSTR + 1], c2 = smp[base + 2 * DSTR + 2];
            uint32_t d0 = smp[base + 3 * DSTR], d1 = smp[base + 3 * DSTR + 1], d2 = smp[base + 3 * DSTR + 2];
            // parity select: (h[lx],h[lx+1]) and (h[lx+2],h[lx+3])
            uint32_t a01 = __builtin_amdgcn_alignbit(a1, a0, sh);
            uint32_t a23 = __builtin_amdgcn_alignbit(a2, a1, sh);
            uint32_t b01 = __builtin_amdgcn_alignbit(b1, b0, sh);
            uint32_t b23 = __builtin_amdgcn_alignbit(b2, b1, sh);
            uint32_t c01 = __builtin_amdgcn_alignbit(c1, c0, sh);
            uint32_t c23 = __builtin_amdgcn_alignbit(c2, c1, sh);
            uint32_t d01 = __builtin_amdgcn_alignbit(d1, d0, sh);
            uint32_t d23 = __builtin_amdgcn_alignbit(d2, d1, sh);
            float s0 = __builtin_amdgcn_fdot2(wxa, u2h(a01),
                         __builtin_amdgcn_fdot2(wxb, u2h(a23), 0.0f, false), false);
            float s1 = __builtin_amdgcn_fdot2(wxa, u2h(b01),
                         __builtin_amdgcn_fdot2(wxb, u2h(b23), 0.0f, false), false);
            float s2 = __builtin_amdgcn_fdot2(wxa, u2h(c01),
                         __builtin_amdgcn_fdot2(wxb, u2h(c23), 0.0f, false), false);
            float s3 = __builtin_amdgcn_fdot2(wxa, u2h(d01),
                         __builtin_amdgcn_fdot2(wxb, u2h(d23), 0.0f, false), false);
            acc = wm1.y * s0 + w0v.y * s1 + w1v.y * s2 + w2v.y * s3;
        } else {
            acc = cubic_gather_global(p, x0, y0, wm1.x, w0v.x, w1v.x, w2v.x,
                                      wm1.y, w0v.y, w1v.y, w2v.y);
        }
        out[didx] = fminf(fmaxf(acc, 0.0f), 1.0f);
    }
}

extern "C" void kernel_launch(void* const* d_in, const int* in_sizes, int n_in,
                              void* d_out, int out_size, void* d_ws, size_t ws_size,
                              hipStream_t stream) {
    const float* img = (const float*)d_in[0];
    const float* dxp = (const float*)d_in[1];
    const float* dyp = (const float*)d_in[2];
    float* out = (float*)d_out;

    const int planes = in_sizes[0] / (HD * WD);  // B*C = 24
    dim3 grid(WD / TILE, HD / TILE, planes);
    bicubic_tile_kernel<<<grid, 256, 0, stream>>>(img, dxp, dyp, out);
}